// Round 10
// baseline (380.434 us; speedup 1.0000x reference)
//
#include <hip/hip_runtime.h>

// Cost volume, D=4: out[b,s,h,w] = mean_c feat1[b,c,h,w] * feat2[b,c,h,w+s-4]
// feat1/feat2: (8, 256, 96, 320) f32; out: (8, 9, 96, 320) f32.
// R6: R5 skeleton (padded-LDS feat2 window, barrier-pinned prefetch) +
//  - depth-3 register prefetch (issue-to-use = 3 iterations >> HBM latency)
//  - fused final reduction: last sibling block (per row-group) sums the 4
//    channel-chunk partials and writes d_out (device-scope atomic + fences;
//    sibling blocks swizzled onto the same XCD for L2-local re-reads).

constexpr int B  = 8;
constexpr int C  = 256;
constexpr int H  = 96;
constexpr int W  = 320;
constexpr int NS = 9;            // 2*D+1 shifts
constexpr int QT = W / 4;        // 80 float4 per row
constexpr int RPB = 4;           // rows per block
constexpr int NTH = RPB * QT;    // 320 threads = 5 waves
constexpr int NC  = 4;           // channel chunks -> 768 blocks = 3/CU
constexpr int CCH = C / NC;      // 64 channels per chunk
constexpr int HW  = H * W;
constexpr int OUT_ELEMS = B * NS * H * W;   // 2,211,840
constexpr int PADW = W + 8;      // 4-float zero halo each side
constexpr int NGRP = B * (H / RPB);         // 192 row-groups
constexpr int GPX  = NGRP / 8;              // 24 groups per XCD slot

__global__ void zero_out_kernel(float* __restrict__ out, int n) {
    int i = blockIdx.x * blockDim.x + threadIdx.x;
    int stride = gridDim.x * blockDim.x;
    for (; i < n; i += stride) out[i] = 0.0f;
}

__global__ void zero_cnt_kernel(int* __restrict__ cnt) {
    int i = threadIdx.x;
    if (i < NGRP) cnt[i] = 0;
}

template <bool FUSED>
__global__ __launch_bounds__(NTH, 4)
void cv_kernel(const float* __restrict__ f1,
               const float* __restrict__ f2,
               float* __restrict__ part,
               int* __restrict__ cnt,
               float* __restrict__ out) {
    __shared__ float bufA[RPB][PADW];
    __shared__ float bufB[RPB][PADW];
    __shared__ int last_flag;

    const int tid = threadIdx.x;
    const int q   = tid % QT;
    const int r   = tid / QT;

    // Swizzle: hw blocks round-robin XCDs by id (heuristic). Decode so the 4
    // sibling chunk-blocks of one row-group share blk&7 -> same XCD L2.
    // Correctness does NOT depend on this mapping (fences below).
    const int x = blockIdx.x & 7;          // 0..7
    const int m = blockIdx.x >> 3;         // 0..95
    const int rowblk = x * GPX + (m % GPX);   // 0..191
    const int cchunk = m / GPX;               // 0..3
    const int hb = rowblk % (H / RPB);
    const int b  = rowblk / (H / RPB);
    const int h  = hb * RPB + r;
    const int c0 = cchunk * CCH;

    const size_t off = ((size_t)(b * C + c0) * H + h) * (size_t)W + 4 * q;
    const float* p1 = f1 + off;
    const float* p2 = f2 + off;

    // Zero the halo pads once (covered by the first STEP's barrier).
    if (q == 0) {
#pragma unroll
        for (int k = 0; k < 4; ++k) { bufA[r][k] = 0.f; bufB[r][k] = 0.f; }
    }
    if (q == QT - 1) {
#pragma unroll
        for (int k = 0; k < 4; ++k) {
            bufA[r][4 + W + k] = 0.f; bufB[r][4 + W + k] = 0.f;
        }
    }

    float acc[4][NS];
#pragma unroll
    for (int j = 0; j < 4; ++j)
#pragma unroll
        for (int s = 0; s < NS; ++s) acc[j][s] = 0.0f;

    // Prologue: channels 0..2 in registers (depth-3 pipeline).
    float4 a0 = *reinterpret_cast<const float4*>(p1);
    float4 r0 = *reinterpret_cast<const float4*>(p2);
    float4 a1 = *reinterpret_cast<const float4*>(p1 + (size_t)HW);
    float4 r1 = *reinterpret_cast<const float4*>(p2 + (size_t)HW);
    float4 a2 = *reinterpret_cast<const float4*>(p1 + 2 * (size_t)HW);
    float4 r2 = *reinterpret_cast<const float4*>(p2 + 2 * (size_t)HW);

    const float* pl1 = p1 + 3 * (size_t)HW;   // next issue address
    const float* pl2 = p2 + 3 * (size_t)HW;
    int cadv = CCH - 4;   // remaining pointer advances (clamp at last channel)

    // One STEP per channel c:
    //   ds_write cur feat2 row -> issue channel c+3's 2 loads (pinned before
    //   the fence) -> lgkmcnt(0) + raw s_barrier (prefetch loads stay in
    //   flight) -> unconditional 12-float window from padded LDS -> 36 FMAs
    //   -> rotate stages.
#define STEP(BUF)                                                          \
    {                                                                      \
        *reinterpret_cast<float4*>(&BUF[r][4 + 4 * q]) = r0;               \
        const float4 an = *reinterpret_cast<const float4*>(pl1);           \
        const float4 rn = *reinterpret_cast<const float4*>(pl2);           \
        const size_t adv = (cadv > 0) ? (size_t)HW : 0;                    \
        --cadv;                                                            \
        pl1 += adv; pl2 += adv;                                            \
        asm volatile("s_waitcnt lgkmcnt(0)" ::: "memory");                 \
        __builtin_amdgcn_s_barrier();                                      \
        asm volatile("" ::: "memory");                                     \
        const float4 x0 = *reinterpret_cast<const float4*>(&BUF[r][4 * q]);\
        const float4 x2 =                                                  \
            *reinterpret_cast<const float4*>(&BUF[r][4 * q + 8]);          \
        const float xw[12] = {x0.x, x0.y, x0.z, x0.w,                      \
                              r0.x, r0.y, r0.z, r0.w,                      \
                              x2.x, x2.y, x2.z, x2.w};                     \
        const float av[4] = {a0.x, a0.y, a0.z, a0.w};                      \
        _Pragma("unroll")                                                  \
        for (int j = 0; j < 4; ++j)                                        \
            _Pragma("unroll")                                              \
            for (int s = 0; s < NS; ++s)                                   \
                acc[j][s] = fmaf(av[j], xw[j + s], acc[j][s]);             \
        a0 = a1; r0 = r1; a1 = a2; r1 = r2; a2 = an; r2 = rn;              \
    }

    // unroll 3 (=6 STEPs) lets renaming absorb the 3-stage rotation moves.
#pragma unroll 3
    for (int c = 0; c < CCH; c += 2) {
        STEP(bufA)
        STEP(bufB)
    }
#undef STEP

    // Store partial sums: part[cchunk][b][s][h][w]
    float* basep = part + (size_t)cchunk * OUT_ELEMS;
#pragma unroll
    for (int s = 0; s < NS; ++s) {
        float4 v = make_float4(acc[0][s], acc[1][s], acc[2][s], acc[3][s]);
        *reinterpret_cast<float4*>(
            basep + ((size_t)(b * NS + s) * H + h) * (size_t)W + 4 * q) = v;
    }

    if (FUSED) {
        // Release our partial stores, count arrival; last sibling reduces.
        __threadfence();
        if (tid == 0) {
            int old = atomicAdd(&cnt[rowblk], 1);   // device-scope by default
            last_flag = (old == NC - 1) ? 1 : 0;
        }
        __syncthreads();
        if (last_flag) {
            __threadfence();   // acquire: invalidate before re-reading partials
            const float scale = 1.0f / (float)C;
#pragma unroll
            for (int s = 0; s < NS; ++s) {
                const size_t o = ((size_t)(b * NS + s) * H + h) * (size_t)W + 4 * q;
                float4 v0 = *reinterpret_cast<const float4*>(part + o);
                float4 v1 = *reinterpret_cast<const float4*>(part + (size_t)OUT_ELEMS + o);
                float4 v2 = *reinterpret_cast<const float4*>(part + 2 * (size_t)OUT_ELEMS + o);
                float4 v3 = *reinterpret_cast<const float4*>(part + 3 * (size_t)OUT_ELEMS + o);
                float4 rr;
                rr.x = (v0.x + v1.x + v2.x + v3.x) * scale;
                rr.y = (v0.y + v1.y + v2.y + v3.y) * scale;
                rr.z = (v0.z + v1.z + v2.z + v3.z) * scale;
                rr.w = (v0.w + v1.w + v2.w + v3.w) * scale;
                *reinterpret_cast<float4*>(out + o) = rr;
            }
        }
    }
}

// Standalone reduce (used when ws has room for partials but not counters).
__global__ void reduce_kernel(const float* __restrict__ part,
                              float* __restrict__ out, int n4) {
    const float scale = 1.0f / (float)C;
    const float4* p = reinterpret_cast<const float4*>(part);
    float4* o = reinterpret_cast<float4*>(out);
    int i = blockIdx.x * blockDim.x + threadIdx.x;
    int stride = gridDim.x * blockDim.x;
    const int n4e = OUT_ELEMS / 4;
    for (; i < n4; i += stride) {
        float4 v0 = p[i];
        float4 v1 = p[i + n4e];
        float4 v2 = p[i + 2 * n4e];
        float4 v3 = p[i + 3 * n4e];
        float4 rr;
        rr.x = (v0.x + v1.x + v2.x + v3.x) * scale;
        rr.y = (v0.y + v1.y + v2.y + v3.y) * scale;
        rr.z = (v0.z + v1.z + v2.z + v3.z) * scale;
        rr.w = (v0.w + v1.w + v2.w + v3.w) * scale;
        o[i] = rr;
    }
}

// Fallback if ws is too small: simple atomic version (correctness only).
__global__ __launch_bounds__(NTH)
void cv_atomic_kernel(const float* __restrict__ f1,
                      const float* __restrict__ f2,
                      float* __restrict__ out) {
    const int tid = threadIdx.x;
    const int q = tid % QT, r = tid / QT;
    const int blk = blockIdx.x;
    const int cchunk = blk % NC;
    const int rowblk = blk / NC;
    const int hb = rowblk % (H / RPB);
    const int b  = rowblk / (H / RPB);
    const int h  = hb * RPB + r;
    const int c0 = cchunk * CCH;

    const size_t off = ((size_t)(b * C + c0) * H + h) * (size_t)W + 4 * q;
    const float* p1 = f1 + off;
    const float* p2 = f2 + off;
    const bool has_lo = (q > 0), has_hi = (q < QT - 1);
    const int lo = has_lo ? -4 : 0, hi = has_hi ? 4 : 0;

    float acc[4][NS];
#pragma unroll
    for (int j = 0; j < 4; ++j)
#pragma unroll
        for (int s = 0; s < NS; ++s) acc[j][s] = 0.0f;

    for (int c = 0; c < CCH; ++c) {
        float4 a  = *reinterpret_cast<const float4*>(p1);
        float4 x0 = *reinterpret_cast<const float4*>(p2 + lo);
        float4 x1 = *reinterpret_cast<const float4*>(p2);
        float4 x2 = *reinterpret_cast<const float4*>(p2 + hi);
        float xw[12] = { has_lo ? x0.x : 0.f, has_lo ? x0.y : 0.f,
                         has_lo ? x0.z : 0.f, has_lo ? x0.w : 0.f,
                         x1.x, x1.y, x1.z, x1.w,
                         has_hi ? x2.x : 0.f, has_hi ? x2.y : 0.f,
                         has_hi ? x2.z : 0.f, has_hi ? x2.w : 0.f };
        float av[4] = {a.x, a.y, a.z, a.w};
#pragma unroll
        for (int j = 0; j < 4; ++j)
#pragma unroll
            for (int s = 0; s < NS; ++s)
                acc[j][s] = fmaf(av[j], xw[j + s], acc[j][s]);
        p1 += HW; p2 += HW;
    }
    const float scale = 1.0f / (float)C;
#pragma unroll
    for (int s = 0; s < NS; ++s)
#pragma unroll
        for (int j = 0; j < 4; ++j)
            atomicAdd(out + ((size_t)(b * NS + s) * H + h) * (size_t)W + 4 * q + j,
                      acc[j][s] * scale);
}

extern "C" void kernel_launch(void* const* d_in, const int* in_sizes, int n_in,
                              void* d_out, int out_size, void* d_ws, size_t ws_size,
                              hipStream_t stream) {
    const float* f1 = (const float*)d_in[0];
    const float* f2 = (const float*)d_in[1];
    float* out = (float*)d_out;

    dim3 grid(B * (H / RPB) * NC);   // 768 blocks
    dim3 block(NTH);                 // 320 threads

    const size_t need_part = (size_t)NC * OUT_ELEMS * sizeof(float);  // 35.4 MB
    const size_t need_full = need_part + NGRP * sizeof(int) + 256;

    if (ws_size >= need_full) {
        float* part = (float*)d_ws;
        int* cnt = (int*)((char*)d_ws + need_part);
        hipLaunchKernelGGL(zero_cnt_kernel, dim3(1), dim3(256), 0, stream, cnt);
        hipLaunchKernelGGL((cv_kernel<true>), grid, block, 0, stream,
                           f1, f2, part, cnt, out);
    } else if (ws_size >= need_part) {
        float* part = (float*)d_ws;
        hipLaunchKernelGGL((cv_kernel<false>), grid, block, 0, stream,
                           f1, f2, part, nullptr, out);
        hipLaunchKernelGGL(reduce_kernel, dim3(2160), dim3(256), 0, stream,
                           part, out, OUT_ELEMS / 4);
    } else {
        hipLaunchKernelGGL(zero_out_kernel, dim3(512), dim3(256), 0, stream,
                           out, out_size);
        hipLaunchKernelGGL(cv_atomic_kernel, grid, block, 0, stream, f1, f2, out);
    }
}

// Round 11
// 200.069 us; speedup vs baseline: 1.9015x; 1.9015x over previous
//
#include <hip/hip_runtime.h>

// Cost volume, D=4: out[b,s,h,w] = mean_c feat1[b,c,h,w] * feat2[b,c,h,w+s-4]
// feat1/feat2: (8, 256, 96, 320) f32; out: (8, 9, 96, 320) f32.
// R11 = R5 skeleton (padded-LDS feat2 window, halo zeroed once, barrier-pinned
// prefetch, separate reduce pass) + depth-3 register prefetch ONLY.
// R10 lesson: NO cross-block fusion, NO __threadfence in the hot kernel —
// device-scope fences evicted the whole working set (WRITE 34->212 MB).

constexpr int B  = 8;
constexpr int C  = 256;
constexpr int H  = 96;
constexpr int W  = 320;
constexpr int NS = 9;            // 2*D+1 shifts
constexpr int QT = W / 4;        // 80 float4 per row
constexpr int RPB = 4;           // rows per block
constexpr int NTH = RPB * QT;    // 320 threads = 5 waves
constexpr int NC  = 4;           // channel chunks -> 768 blocks = 3/CU
constexpr int CCH = C / NC;      // 64 channels per chunk
constexpr int HW  = H * W;
constexpr int OUT_ELEMS = B * NS * H * W;   // 2,211,840
constexpr int PADW = W + 8;      // 4-float zero halo each side

__global__ void zero_out_kernel(float* __restrict__ out, int n) {
    int i = blockIdx.x * blockDim.x + threadIdx.x;
    int stride = gridDim.x * blockDim.x;
    for (; i < n; i += stride) out[i] = 0.0f;
}

__global__ __launch_bounds__(NTH, 4)
void cv_kernel(const float* __restrict__ f1,
               const float* __restrict__ f2,
               float* __restrict__ part) {
    __shared__ float bufA[RPB][PADW];
    __shared__ float bufB[RPB][PADW];

    const int tid = threadIdx.x;
    const int q   = tid % QT;
    const int r   = tid / QT;

    const int blk    = blockIdx.x;
    const int cchunk = blk % NC;
    const int rowblk = blk / NC;
    const int hb     = rowblk % (H / RPB);
    const int b      = rowblk / (H / RPB);
    const int h      = hb * RPB + r;
    const int c0     = cchunk * CCH;

    const size_t off = ((size_t)(b * C + c0) * H + h) * (size_t)W + 4 * q;
    const float* p1 = f1 + off;
    const float* p2 = f2 + off;

    // Zero the halo pads once (covered by the first STEP's barrier).
    if (q == 0) {
#pragma unroll
        for (int k = 0; k < 4; ++k) { bufA[r][k] = 0.f; bufB[r][k] = 0.f; }
    }
    if (q == QT - 1) {
#pragma unroll
        for (int k = 0; k < 4; ++k) {
            bufA[r][4 + W + k] = 0.f; bufB[r][4 + W + k] = 0.f;
        }
    }

    float acc[4][NS];
#pragma unroll
    for (int j = 0; j < 4; ++j)
#pragma unroll
        for (int s = 0; s < NS; ++s) acc[j][s] = 0.0f;

    // Prologue: channels 0..2 in registers (depth-3 pipeline).
    float4 a0 = *reinterpret_cast<const float4*>(p1);
    float4 r0 = *reinterpret_cast<const float4*>(p2);
    float4 a1 = *reinterpret_cast<const float4*>(p1 + (size_t)HW);
    float4 r1 = *reinterpret_cast<const float4*>(p2 + (size_t)HW);
    float4 a2 = *reinterpret_cast<const float4*>(p1 + 2 * (size_t)HW);
    float4 r2 = *reinterpret_cast<const float4*>(p2 + 2 * (size_t)HW);

    const float* pl1 = p1 + 3 * (size_t)HW;   // next issue address
    const float* pl2 = p2 + 3 * (size_t)HW;
    int cadv = CCH - 4;   // remaining pointer advances (clamp at last channel)

    // One STEP per channel c:
    //   ds_write cur feat2 row -> issue channel c+3's 2 loads (pinned before
    //   the fence) -> lgkmcnt(0) + raw s_barrier (prefetch loads stay in
    //   flight across it) -> unconditional 12-float window from padded LDS
    //   -> 36 FMAs -> rotate stages.
#define STEP(BUF)                                                          \
    {                                                                      \
        *reinterpret_cast<float4*>(&BUF[r][4 + 4 * q]) = r0;               \
        const float4 an = *reinterpret_cast<const float4*>(pl1);           \
        const float4 rn = *reinterpret_cast<const float4*>(pl2);           \
        const size_t adv = (cadv > 0) ? (size_t)HW : 0;                    \
        --cadv;                                                            \
        pl1 += adv; pl2 += adv;                                            \
        asm volatile("s_waitcnt lgkmcnt(0)" ::: "memory");                 \
        __builtin_amdgcn_s_barrier();                                      \
        asm volatile("" ::: "memory");                                     \
        const float4 x0 = *reinterpret_cast<const float4*>(&BUF[r][4 * q]);\
        const float4 x2 =                                                  \
            *reinterpret_cast<const float4*>(&BUF[r][4 * q + 8]);          \
        const float xw[12] = {x0.x, x0.y, x0.z, x0.w,                      \
                              r0.x, r0.y, r0.z, r0.w,                      \
                              x2.x, x2.y, x2.z, x2.w};                     \
        const float av[4] = {a0.x, a0.y, a0.z, a0.w};                      \
        _Pragma("unroll")                                                  \
        for (int j = 0; j < 4; ++j)                                        \
            _Pragma("unroll")                                              \
            for (int s = 0; s < NS; ++s)                                   \
                acc[j][s] = fmaf(av[j], xw[j + s], acc[j][s]);             \
        a0 = a1; r0 = r1; a1 = a2; r1 = r2; a2 = an; r2 = rn;              \
    }

    // unroll 3 (= 6 STEPs = LCM of 3-stage rotation x 2 LDS buffers) lets
    // register renaming absorb the rotation moves.
#pragma unroll 3
    for (int c = 0; c < CCH; c += 2) {
        STEP(bufA)
        STEP(bufB)
    }
#undef STEP

    // Store partial sums: part[cchunk][b][s][h][w]
    float* basep = part + (size_t)cchunk * OUT_ELEMS;
#pragma unroll
    for (int s = 0; s < NS; ++s) {
        float4 v = make_float4(acc[0][s], acc[1][s], acc[2][s], acc[3][s]);
        *reinterpret_cast<float4*>(
            basep + ((size_t)(b * NS + s) * H + h) * (size_t)W + 4 * q) = v;
    }
}

__global__ void reduce_kernel(const float* __restrict__ part,
                              float* __restrict__ out, int n4) {
    const float scale = 1.0f / (float)C;
    const float4* p = reinterpret_cast<const float4*>(part);
    float4* o = reinterpret_cast<float4*>(out);
    int i = blockIdx.x * blockDim.x + threadIdx.x;
    int stride = gridDim.x * blockDim.x;
    const int n4e = OUT_ELEMS / 4;
    for (; i < n4; i += stride) {
        float4 v0 = p[i];
        float4 v1 = p[i + n4e];
        float4 v2 = p[i + 2 * n4e];
        float4 v3 = p[i + 3 * n4e];
        float4 rr;
        rr.x = (v0.x + v1.x + v2.x + v3.x) * scale;
        rr.y = (v0.y + v1.y + v2.y + v3.y) * scale;
        rr.z = (v0.z + v1.z + v2.z + v3.z) * scale;
        rr.w = (v0.w + v1.w + v2.w + v3.w) * scale;
        o[i] = rr;
    }
}

// Fallback if ws is too small: simple atomic version (correctness only).
__global__ __launch_bounds__(NTH)
void cv_atomic_kernel(const float* __restrict__ f1,
                      const float* __restrict__ f2,
                      float* __restrict__ out) {
    const int tid = threadIdx.x;
    const int q = tid % QT, r = tid / QT;
    const int blk = blockIdx.x;
    const int cchunk = blk % NC;
    const int rowblk = blk / NC;
    const int hb = rowblk % (H / RPB);
    const int b  = rowblk / (H / RPB);
    const int h  = hb * RPB + r;
    const int c0 = cchunk * CCH;

    const size_t off = ((size_t)(b * C + c0) * H + h) * (size_t)W + 4 * q;
    const float* p1 = f1 + off;
    const float* p2 = f2 + off;
    const bool has_lo = (q > 0), has_hi = (q < QT - 1);
    const int lo = has_lo ? -4 : 0, hi = has_hi ? 4 : 0;

    float acc[4][NS];
#pragma unroll
    for (int j = 0; j < 4; ++j)
#pragma unroll
        for (int s = 0; s < NS; ++s) acc[j][s] = 0.0f;

    for (int c = 0; c < CCH; ++c) {
        float4 a  = *reinterpret_cast<const float4*>(p1);
        float4 x0 = *reinterpret_cast<const float4*>(p2 + lo);
        float4 x1 = *reinterpret_cast<const float4*>(p2);
        float4 x2 = *reinterpret_cast<const float4*>(p2 + hi);
        float xw[12] = { has_lo ? x0.x : 0.f, has_lo ? x0.y : 0.f,
                         has_lo ? x0.z : 0.f, has_lo ? x0.w : 0.f,
                         x1.x, x1.y, x1.z, x1.w,
                         has_hi ? x2.x : 0.f, has_hi ? x2.y : 0.f,
                         has_hi ? x2.z : 0.f, has_hi ? x2.w : 0.f };
        float av[4] = {a.x, a.y, a.z, a.w};
#pragma unroll
        for (int j = 0; j < 4; ++j)
#pragma unroll
            for (int s = 0; s < NS; ++s)
                acc[j][s] = fmaf(av[j], xw[j + s], acc[j][s]);
        p1 += HW; p2 += HW;
    }
    const float scale = 1.0f / (float)C;
#pragma unroll
    for (int s = 0; s < NS; ++s)
#pragma unroll
        for (int j = 0; j < 4; ++j)
            atomicAdd(out + ((size_t)(b * NS + s) * H + h) * (size_t)W + 4 * q + j,
                      acc[j][s] * scale);
}

extern "C" void kernel_launch(void* const* d_in, const int* in_sizes, int n_in,
                              void* d_out, int out_size, void* d_ws, size_t ws_size,
                              hipStream_t stream) {
    const float* f1 = (const float*)d_in[0];
    const float* f2 = (const float*)d_in[1];
    float* out = (float*)d_out;

    dim3 grid(B * (H / RPB) * NC);   // 768 blocks
    dim3 block(NTH);                 // 320 threads

    const size_t need = (size_t)NC * OUT_ELEMS * sizeof(float);  // 35.4 MB
    if (ws_size >= need) {
        float* part = (float*)d_ws;
        hipLaunchKernelGGL(cv_kernel, grid, block, 0, stream, f1, f2, part);
        hipLaunchKernelGGL(reduce_kernel, dim3(2160), dim3(256), 0, stream,
                           part, out, OUT_ELEMS / 4);
    } else {
        hipLaunchKernelGGL(zero_out_kernel, dim3(512), dim3(256), 0, stream,
                           out, out_size);
        hipLaunchKernelGGL(cv_atomic_kernel, grid, block, 0, stream, f1, f2, out);
    }
}

// Round 12
// 123.696 us; speedup vs baseline: 3.0755x; 1.6174x over previous
//
#include <hip/hip_runtime.h>

// Cost volume, D=4: out[b,s,h,w] = mean_c feat1[b,c,h,w] * feat2[b,c,h,w+s-4]
// feat1/feat2: (8, 256, 96, 320) f32; out: (8, 9, 96, 320) f32.
// R12 = R5's proven main loop (padded-LDS feat2 window, halo zeroed once,
// depth-1 barrier-pinned prefetch: ds_write -> load next -> lgkmcnt(0) ->
// raw s_barrier -> window reads -> 36 FMA), with the channel split moved
// INSIDE the block: tid = q*4 + r, thread owns channels r, r+4, ... (64
// iters). The 4 channel-siblings are adjacent lanes -> final reduce is a
// 2-step shfl_xor butterfly + direct coalesced d_out write.
// Kills the 35.4 MB partial write + 44 MB reduce pass of R5.
// R11 lesson: NO deep register prefetch (spills -> 156 MB scratch writes).
// R10 lesson: NO cross-block fusion / device fences.

constexpr int B  = 8;
constexpr int C  = 256;
constexpr int H  = 96;
constexpr int W  = 320;
constexpr int NS = 9;              // 2*D+1 shifts
constexpr int QT = W / 4;          // 80 float4 per row
constexpr int NTH = QT * 4;        // 320 threads: tid = q*4 + r
constexpr int HW  = H * W;
constexpr int CH_STRIDE = 4 * HW;  // per-thread channel step (4 channels/iter)
constexpr int ITERS = C / 4;       // 64 iterations per thread
constexpr int PADW = W + 8;        // 4-float zero halo each side

__global__ __launch_bounds__(NTH, 4)
void cv_kernel(const float* __restrict__ f1,
               const float* __restrict__ f2,
               float* __restrict__ out) {
    __shared__ float bufA[4][PADW];   // one h-row x 4 channels (r-groups)
    __shared__ float bufB[4][PADW];   // double buffer; 10.5 KB total

    const int tid = threadIdx.x;
    const int q   = tid >> 2;         // float4 index within the row
    const int r   = tid & 3;          // channel sub-group (adjacent lanes!)

    const int blk = blockIdx.x;       // 768 blocks = one per (b,h) row
    const int h   = blk % H;
    const int b   = blk / H;

    const size_t off = ((size_t)(b * C + r) * H + h) * (size_t)W + 4 * q;
    const float* p1 = f1 + off;
    const float* p2 = f2 + off;

    // Zero the halo pads once (covered by the first STEP's barrier).
    // q==0 lanes are tid 0..3 -> each r-row zeroed by its own lane.
    if (q == 0) {
#pragma unroll
        for (int k = 0; k < 4; ++k) { bufA[r][k] = 0.f; bufB[r][k] = 0.f; }
    }
    if (q == QT - 1) {
#pragma unroll
        for (int k = 0; k < 4; ++k) {
            bufA[r][4 + W + k] = 0.f; bufB[r][4 + W + k] = 0.f;
        }
    }

    float acc[4][NS];
#pragma unroll
    for (int j = 0; j < 4; ++j)
#pragma unroll
        for (int s = 0; s < NS; ++s) acc[j][s] = 0.0f;

    // Prologue: this thread's channel r in registers (depth-1, R5-proven).
    float4 a_cur = *reinterpret_cast<const float4*>(p1);
    float4 r_cur = *reinterpret_cast<const float4*>(p2);
    int cnext = 1;   // clamped at last iter (dummy re-load, L1-hot, unused)

    // One STEP per channel-iteration:
    //   ds_write cur feat2 row -> issue next channel's 2 loads (pinned
    //   before the fence) -> lgkmcnt(0) + raw s_barrier (prefetch loads
    //   stay in flight across it) -> unconditional 12-float window from
    //   padded LDS (middle 4 from register) -> 36 FMAs -> rotate.
#define STEP(BUF)                                                          \
    {                                                                      \
        *reinterpret_cast<float4*>(&BUF[r][4 + 4 * q]) = r_cur;            \
        const float4 a_nxt = *reinterpret_cast<const float4*>(             \
            p1 + (size_t)cnext * CH_STRIDE);                               \
        const float4 r_nxt = *reinterpret_cast<const float4*>(             \
            p2 + (size_t)cnext * CH_STRIDE);                               \
        cnext = (cnext < ITERS - 1) ? cnext + 1 : cnext;                   \
        asm volatile("s_waitcnt lgkmcnt(0)" ::: "memory");                 \
        __builtin_amdgcn_s_barrier();                                      \
        asm volatile("" ::: "memory");                                     \
        const float4 x0 = *reinterpret_cast<const float4*>(&BUF[r][4 * q]);\
        const float4 x2 =                                                  \
            *reinterpret_cast<const float4*>(&BUF[r][4 * q + 8]);          \
        const float xw[12] = {x0.x, x0.y, x0.z, x0.w,                      \
                              r_cur.x, r_cur.y, r_cur.z, r_cur.w,          \
                              x2.x, x2.y, x2.z, x2.w};                     \
        const float av[4] = {a_cur.x, a_cur.y, a_cur.z, a_cur.w};          \
        _Pragma("unroll")                                                  \
        for (int j = 0; j < 4; ++j)                                        \
            _Pragma("unroll")                                              \
            for (int s = 0; s < NS; ++s)                                   \
                acc[j][s] = fmaf(av[j], xw[j + s], acc[j][s]);             \
        a_cur = a_nxt; r_cur = r_nxt;                                      \
    }

#pragma unroll 1
    for (int c = 0; c < ITERS; c += 2) {
        STEP(bufA)
        STEP(bufB)
    }
#undef STEP

    // Cross-channel reduce: the 4 r-siblings of a q-group are lanes
    // q*4+0..3 -> 2-step shfl_xor butterfly, all 4 lanes end with the sum.
#pragma unroll
    for (int j = 0; j < 4; ++j)
#pragma unroll
        for (int s = 0; s < NS; ++s) {
            float v = acc[j][s];
            v += __shfl_xor(v, 1, 64);
            v += __shfl_xor(v, 2, 64);
            acc[j][s] = v;
        }

    // Direct output write, split across the 4 sibling lanes: lane r writes
    // shifts s = r, r+4, r+8. For fixed s a wave's 16 active lanes write
    // 256 B contiguous -> coalesced.
    const float scale = 1.0f / (float)C;
#pragma unroll
    for (int s = r; s < NS; s += 4) {
        float4 v = make_float4(acc[0][s] * scale, acc[1][s] * scale,
                               acc[2][s] * scale, acc[3][s] * scale);
        *reinterpret_cast<float4*>(
            out + ((size_t)(b * NS + s) * H + h) * (size_t)W + 4 * q) = v;
    }
}

extern "C" void kernel_launch(void* const* d_in, const int* in_sizes, int n_in,
                              void* d_out, int out_size, void* d_ws, size_t ws_size,
                              hipStream_t stream) {
    const float* f1 = (const float*)d_in[0];
    const float* f2 = (const float*)d_in[1];
    float* out = (float*)d_out;

    dim3 grid(B * H);    // 768 blocks = 3 per CU
    dim3 block(NTH);     // 320 threads = 5 waves
    hipLaunchKernelGGL(cv_kernel, grid, block, 0, stream, f1, f2, out);
}

// Round 13
// 121.400 us; speedup vs baseline: 3.1337x; 1.0189x over previous
//
#include <hip/hip_runtime.h>

// Cost volume, D=4: out[b,s,h,w] = mean_c feat1[b,c,h,w] * feat2[b,c,h,w+s-4]
// feat1/feat2: (8, 256, 96, 320) f32; out: (8, 9, 96, 320) f32.
// R13 single-kernel: R5's PROVEN main-loop geometry (r = tid/80 -> every wave
// contiguous within a row, 1KB wave loads; padded-LDS feat2 window; depth-1
// barrier-pinned prefetch) with r indexing CHANNEL sub-groups (c = 4*iter+r),
// plus an LDS-transpose epilogue: per s-plane stage acc to LDS, sync, all 320
// threads write one dense 1280B row. Deletes the partial-sum round trip AND
// R12's 7x write amplification (divergent multi-plane stores).
// R12 lesson: never mix channels inside a wave (4x split loads) and never
// emit divergent multi-plane stores (62 MB HBM writes for 8.85 MB of data).
// R11 lesson: no deep register prefetch (spills). R10: no fences/fusion.

constexpr int B  = 8;
constexpr int C  = 256;
constexpr int H  = 96;
constexpr int W  = 320;
constexpr int NS = 9;              // 2*D+1 shifts
constexpr int QT = W / 4;          // 80 float4 per row
constexpr int NTH = QT * 4;        // 320 threads: tid = r*80 + q
constexpr int HW  = H * W;
constexpr int CH_STRIDE = 4 * HW;  // channel-group step (4 channels/iter)
constexpr int ITERS = C / 4;       // 64 iterations per thread
constexpr int PADW = W + 8;        // 4-float zero halo each side

__global__ __launch_bounds__(NTH, 4)
void cv_kernel(const float* __restrict__ f1,
               const float* __restrict__ f2,
               float* __restrict__ out) {
    __shared__ float bufA[4][PADW];   // feat2 rows, one per channel sub-group
    __shared__ float bufB[4][PADW];   // double buffer; 10.5 KB total

    const int tid = threadIdx.x;
    const int q   = tid % QT;         // float4 index within the row
    const int r   = tid / QT;         // channel sub-group (wave-contiguous!)

    const int blk = blockIdx.x;       // 768 blocks = one per (b,h) row
    const int h   = blk % H;
    const int b   = blk / H;

    const size_t off = ((size_t)(b * C + r) * H + h) * (size_t)W + 4 * q;
    const float* p1 = f1 + off;
    const float* p2 = f2 + off;

    // Zero the halo pads once (covered by the first STEP's barrier).
    if (q == 0) {
#pragma unroll
        for (int k = 0; k < 4; ++k) { bufA[r][k] = 0.f; bufB[r][k] = 0.f; }
    }
    if (q == QT - 1) {
#pragma unroll
        for (int k = 0; k < 4; ++k) {
            bufA[r][4 + W + k] = 0.f; bufB[r][4 + W + k] = 0.f;
        }
    }

    float acc[4][NS];
#pragma unroll
    for (int j = 0; j < 4; ++j)
#pragma unroll
        for (int s = 0; s < NS; ++s) acc[j][s] = 0.0f;

    // Prologue: channel r in registers (depth-1, R5-proven).
    float4 a_cur = *reinterpret_cast<const float4*>(p1);
    float4 r_cur = *reinterpret_cast<const float4*>(p2);
    int cnext = 1;   // clamped at last iter (dummy re-load, L1-hot, unused)

    // One STEP per channel-iteration (identical to R5's proven loop):
    //   ds_write cur feat2 row -> issue next channel-group's 2 loads (pinned
    //   before the fence) -> lgkmcnt(0) + raw s_barrier (prefetch loads stay
    //   in flight across it) -> unconditional 12-float window from padded
    //   LDS (middle 4 from register) -> 36 FMAs -> rotate.
#define STEP(BUF)                                                          \
    {                                                                      \
        *reinterpret_cast<float4*>(&BUF[r][4 + 4 * q]) = r_cur;            \
        const float4 a_nxt = *reinterpret_cast<const float4*>(             \
            p1 + (size_t)cnext * CH_STRIDE);                               \
        const float4 r_nxt = *reinterpret_cast<const float4*>(             \
            p2 + (size_t)cnext * CH_STRIDE);                               \
        cnext = (cnext < ITERS - 1) ? cnext + 1 : cnext;                   \
        asm volatile("s_waitcnt lgkmcnt(0)" ::: "memory");                 \
        __builtin_amdgcn_s_barrier();                                      \
        asm volatile("" ::: "memory");                                     \
        const float4 x0 = *reinterpret_cast<const float4*>(&BUF[r][4 * q]);\
        const float4 x2 =                                                  \
            *reinterpret_cast<const float4*>(&BUF[r][4 * q + 8]);          \
        const float xw[12] = {x0.x, x0.y, x0.z, x0.w,                      \
                              r_cur.x, r_cur.y, r_cur.z, r_cur.w,          \
                              x2.x, x2.y, x2.z, x2.w};                     \
        const float av[4] = {a_cur.x, a_cur.y, a_cur.z, a_cur.w};          \
        _Pragma("unroll")                                                  \
        for (int j = 0; j < 4; ++j)                                        \
            _Pragma("unroll")                                              \
            for (int s = 0; s < NS; ++s)                                   \
                acc[j][s] = fmaf(av[j], xw[j + s], acc[j][s]);             \
        a_cur = a_nxt; r_cur = r_nxt;                                      \
    }

#pragma unroll 1
    for (int c = 0; c < ITERS; c += 2) {
        STEP(bufA)
        STEP(bufB)
    }
#undef STEP

    // Epilogue: per s-plane LDS transpose + dense coalesced write.
    // bufA[4][PADW] holds one plane: bufA[r][w] = acc contribution of
    // channel sub-group r at w. All 320 threads then write 4B each ->
    // each wave stores 256B contiguous, full 64B lines, one 1280B row.
    const float scale = 1.0f / (float)C;
    float* orow = out + ((size_t)b * NS * H + h) * (size_t)W;
#pragma unroll 1
    for (int s = 0; s < NS; ++s) {
        __syncthreads();   // previous plane's reads done / main-loop buffers free
        *reinterpret_cast<float4*>(&bufA[r][4 * q]) =
            make_float4(acc[0][s], acc[1][s], acc[2][s], acc[3][s]);
        __syncthreads();
        const int w = tid;   // 0..319
        const float v = (bufA[0][w] + bufA[1][w] + bufA[2][w] + bufA[3][w]) * scale;
        orow[(size_t)s * H * W + w] = v;
    }
}

extern "C" void kernel_launch(void* const* d_in, const int* in_sizes, int n_in,
                              void* d_out, int out_size, void* d_ws, size_t ws_size,
                              hipStream_t stream) {
    const float* f1 = (const float*)d_in[0];
    const float* f2 = (const float*)d_in[1];
    float* out = (float*)d_out;

    dim3 grid(B * H);    // 768 blocks = 3 per CU
    dim3 block(NTH);     // 320 threads = 5 waves
    hipLaunchKernelGGL(cv_kernel, grid, block, 0, stream, f1, f2, out);
}